// Round 16
// baseline (114.732 us; speedup 1.0000x reference)
//
#include <hip/hip_runtime.h>
#include <stdint.h>

typedef uint16_t u16;
typedef __attribute__((ext_vector_type(8))) short short8;
typedef __attribute__((ext_vector_type(4))) float f32x4;

#define DEV static __device__ __forceinline__

DEV u16 f2bf(float f) {
  uint32_t u = __float_as_uint(f);
  return (u16)((u + 0x7fffu + ((u >> 16) & 1u)) >> 16);
}
DEV float bf2f(u16 h) { return __uint_as_float(((uint32_t)h) << 16); }

DEV void gload16(const void* g, void* l) {
  __builtin_amdgcn_global_load_lds(
      (const __attribute__((address_space(1))) void*)g,
      (__attribute__((address_space(3))) void*)l, 16, 0, 0);
}

// ---- fused prep: x cast (blocks 0..4095), Wqkv^T (4096..4863),
// ---- Wout^T (4864..5119). One launch instead of three.
__global__ void k_prep(const float* __restrict__ x, u16* __restrict__ xb,
                       const float* __restrict__ Wqkv, u16* __restrict__ wqkvT,
                       const float* __restrict__ Wout, u16* __restrict__ woutT) {
  __shared__ u16 t[64][65];
  int b = blockIdx.x, tid = threadIdx.x;
  if (b < 4096) {
    int i = b * 256 + tid;
    float4 v = ((const float4*)x)[i];
    uint2 p;
    p.x = (uint32_t)f2bf(v.x) | ((uint32_t)f2bf(v.y) << 16);
    p.y = (uint32_t)f2bf(v.z) | ((uint32_t)f2bf(v.w) << 16);
    ((uint2*)xb)[i] = p;
    return;
  }
  const float* Wm;
  u16* Wt;
  int id, NX;
  if (b < 4864) { Wm = Wqkv; Wt = wqkvT; id = b - 4096; NX = 48; }
  else          { Wm = Wout; Wt = woutT; id = b - 4864; NX = 16; }
  int n0 = (id % NX) * 64, k0 = (id / NX) * 64;
  int K = 1024, N = NX * 64;
#pragma unroll
  for (int i = 0; i < 16; ++i) {
    int idx = tid + i * 256, r = idx >> 6, c = idx & 63;
    t[r][c] = f2bf(Wm[(size_t)(k0 + r) * N + n0 + c]);
  }
  __syncthreads();
#pragma unroll
  for (int i = 0; i < 16; ++i) {
    int idx = tid + i * 256, r = idx >> 6, c = idx & 63;
    Wt[(size_t)(n0 + r) * K + k0 + c] = t[c][r];
  }
}

// Row-pair LDS swizzle for BK=32 slots (64 lines x 128B, 3-bit block XOR):
// LDS(L, b') holds global(row = 2L + (bb>>2), colblk = bb&3), bb = b'^(L&7).
// Reader: addr16(row, lg) = (row>>1)*64 + (((((row&1)<<2)|lg) ^ ((row>>1)&7))*8.
// 8 lanes per 16B block = 2 lanes/bank = conflict-free.
#define AIDX(row, lg) ((((row) >> 1) << 6) + ((((((row) & 1) << 2) | (lg)) ^ (((row) >> 1) & 7)) << 3))

// ---- fused QKV GEMM v10: 128x128, BK=32, RING-3 + RAW barrier --------
// The counted vmcnt finally runs: __syncthreads (which drains vmcnt to 0
// before s_barrier - the m97 ~20% stall) replaced by raw s_barrier with
// compiler fences. Loop: stage(t+2) | ds_read(t) | 16 MFMA | vmcnt(4)
// (certifies t+1, t+2's 4 loads FLY ACROSS the barrier) | s_barrier.
// 48KiB LDS -> 3 blocks/CU; 768 blocks = exactly 3/CU.
__global__ __launch_bounds__(256) void k_gemmqkv(
    const u16* __restrict__ A, const u16* __restrict__ Bt,
    const float* __restrict__ bias,
    const float* __restrict__ qg, const float* __restrict__ qb,
    const float* __restrict__ kg, const float* __restrict__ kb,
    u16* __restrict__ Qn, u16* __restrict__ Kn, u16* __restrict__ Vt) {
  const int K = 1024, N = 3072;
  __shared__ __attribute__((aligned(16))) u16 SA[3][4096];  // 8KiB/slot
  __shared__ __attribute__((aligned(16))) u16 SB[3][4096];
  int bid = blockIdx.x;
  int xcd = bid & 7, i = bid >> 3;        // i in [0,96)
  int my = i / 3, nx = xcd * 3 + i % 3;   // 2D chunk: 3 B-panels per XCD
  int m0 = my * 128, n0 = nx * 128;
  int tid = threadIdx.x, lane = tid & 63, w = tid >> 6;
  int wr = (w >> 1) * 64, wc = (w & 1) * 64;
  int lr = lane & 15, lg = lane >> 4;
  // stager precompute (inverse swizzle on global source, linear LDS dest)
  int Ls = tid >> 3, bs = tid & 7;
  int sbb = bs ^ (Ls & 7);
  int r0 = 2 * Ls + (sbb >> 2);           // row in [0,64)
  int sc = (sbb & 3) * 8;                 // u16 col offset in [0,32)
  f32x4 acc[4][4];
#pragma unroll
  for (int ii = 0; ii < 4; ++ii)
#pragma unroll
    for (int j = 0; j < 4; ++j) acc[ii][j] = (f32x4){0.f, 0.f, 0.f, 0.f};

  int nk = K >> 5;  // 32

#define STGQ(slot, kt)                                                              \
  do {                                                                              \
    gload16(A + (size_t)(m0 + r0) * K + (kt) * 32 + sc, &SA[slot][tid * 8]);        \
    gload16(A + (size_t)(m0 + 64 + r0) * K + (kt) * 32 + sc, &SA[slot][2048 + tid * 8]); \
    gload16(Bt + (size_t)(n0 + r0) * K + (kt) * 32 + sc, &SB[slot][tid * 8]);       \
    gload16(Bt + (size_t)(n0 + 64 + r0) * K + (kt) * 32 + sc, &SB[slot][2048 + tid * 8]); \
  } while (0)

  STGQ(0, 0);
  STGQ(1, 1);
  asm volatile("s_waitcnt vmcnt(4)" ::: "memory");  // tile 0 certified
  __builtin_amdgcn_s_barrier();
  asm volatile("" ::: "memory");

  int cur = 0;
  for (int t = 0; t < nk; ++t) {
    if (t + 2 < nk) {
      int stg = cur + 2; if (stg >= 3) stg -= 3;
      STGQ(stg, t + 2);
    }
    short8 af[4], bfr[4];
#pragma unroll
    for (int mi = 0; mi < 4; ++mi)
      af[mi] = *(const short8*)&SA[cur][AIDX(wr + mi * 16 + lr, lg)];
#pragma unroll
    for (int ni = 0; ni < 4; ++ni)
      bfr[ni] = *(const short8*)&SB[cur][AIDX(wc + ni * 16 + lr, lg)];
    __builtin_amdgcn_s_setprio(1);
#pragma unroll
    for (int mi = 0; mi < 4; ++mi)
#pragma unroll
      for (int ni = 0; ni < 4; ++ni)
        acc[mi][ni] = __builtin_amdgcn_mfma_f32_16x16x32_bf16(af[mi], bfr[ni], acc[mi][ni], 0, 0, 0);
    __builtin_amdgcn_s_setprio(0);
    if (t + 2 < nk)
      asm volatile("s_waitcnt vmcnt(4)" ::: "memory");  // t+1 certified; t+2 in flight
    else if (t + 1 < nk)
      asm volatile("s_waitcnt vmcnt(0)" ::: "memory");
    __builtin_amdgcn_s_barrier();
    asm volatile("" ::: "memory");
    ++cur; if (cur == 3) cur = 0;
  }
#undef STGQ

  int rg = lg * 4;
  int sec = n0 >> 10;                       // 0=Q, 1=K, 2=V
  int hh = ((n0 + wc) >> 6) & 15;           // head for this wave
  int b = m0 >> 11;
  int s0 = m0 & 2047;

  if (sec < 2) {
    const float* gp = sec ? kg : qg;
    const float* bp = sec ? kb : qb;
    float scl = sec ? 1.f : (0.125f * 1.44269504f);  // Q: fold 1/sqrt(D)*log2e
    u16* op = sec ? Kn : Qn;
    float gv[4], bev[4], bb[4];
#pragma unroll
    for (int ni = 0; ni < 4; ++ni) {
      int d = ni * 16 + lr;
      gv[ni] = gp[d];
      bev[ni] = bp[d];
      bb[ni] = bias[n0 + wc + d];
    }
    size_t hb = (size_t)(b * 16 + hh) * 2048 * 64;
#pragma unroll
    for (int mi = 0; mi < 4; ++mi) {
      float a[4][4], ps[4], ps2[4];
#pragma unroll
      for (int ni = 0; ni < 4; ++ni)
#pragma unroll
        for (int j = 0; j < 4; ++j) a[ni][j] = acc[mi][ni][j] + bb[ni];
#pragma unroll
      for (int j = 0; j < 4; ++j) {
        ps[j] = a[0][j] + a[1][j] + a[2][j] + a[3][j];
        ps2[j] = a[0][j] * a[0][j] + a[1][j] * a[1][j] + a[2][j] * a[2][j] + a[3][j] * a[3][j];
      }
#pragma unroll
      for (int m = 1; m < 16; m <<= 1)
#pragma unroll
        for (int j = 0; j < 4; ++j) {
          ps[j] += __shfl_xor(ps[j], m, 64);
          ps2[j] += __shfl_xor(ps2[j], m, 64);
        }
#pragma unroll
      for (int j = 0; j < 4; ++j) {
        float mean = ps[j] * (1.f / 64);
        float var = ps2[j] * (1.f / 64) - mean * mean;
        float r = rsqrtf(var + 1e-5f);
        int row = s0 + wr + mi * 16 + rg + j;
        size_t base = hb + (size_t)row * 64;
#pragma unroll
        for (int ni = 0; ni < 4; ++ni) {
          float v = ((a[ni][j] - mean) * r * gv[ni] + bev[ni]) * scl;
          op[base + ni * 16 + lr] = f2bf(v);
        }
      }
    }
  } else {
    // V: direct transposed store Vt[bh][d][s], 8B packed (4 consecutive s)
    u16* vbase = Vt + (size_t)(b * 16 + hh) * 64 * 2048;
#pragma unroll
    for (int ni = 0; ni < 4; ++ni) {
      int d = ni * 16 + lr;
      float bb = bias[n0 + wc + d];
#pragma unroll
      for (int mi = 0; mi < 4; ++mi) {
        int row0 = s0 + wr + mi * 16 + rg;
        uint2 pk;
        pk.x = (uint32_t)f2bf(acc[mi][ni][0] + bb) | ((uint32_t)f2bf(acc[mi][ni][1] + bb) << 16);
        pk.y = (uint32_t)f2bf(acc[mi][ni][2] + bb) | ((uint32_t)f2bf(acc[mi][ni][3] + bb) << 16);
        *(uint2*)(vbase + (size_t)d * 2048 + row0) = pk;
      }
    }
  }
}

// ---- GEMM2 v10: 128x128, BK=32, RING-3 + RAW barrier (same scheme) ----
template <int OUT_BF16>
__global__ __launch_bounds__(256) void k_gemm5(
    const u16* __restrict__ A, const u16* __restrict__ Bt,
    const float* __restrict__ bias, void* __restrict__ Cout,
    int M, int N, int K) {
  __shared__ __attribute__((aligned(16))) u16 SA[3][4096];
  __shared__ __attribute__((aligned(16))) u16 SB[3][4096];
  int bid = blockIdx.x;
  int ntn = N >> 7;
  int cpx = gridDim.x >> 3;
  int wg = (bid & 7) * cpx + (bid >> 3);
  int my = wg / ntn, nx = wg - my * ntn;
  int m0 = my * 128, n0 = nx * 128;
  int tid = threadIdx.x, lane = tid & 63, w = tid >> 6;
  int wr = (w >> 1) * 64, wc = (w & 1) * 64;
  int lr = lane & 15, lg = lane >> 4;
  int Ls = tid >> 3, bs = tid & 7;
  int sbb = bs ^ (Ls & 7);
  int r0 = 2 * Ls + (sbb >> 2);
  int sc = (sbb & 3) * 8;
  f32x4 acc[4][4];
#pragma unroll
  for (int i = 0; i < 4; ++i)
#pragma unroll
    for (int j = 0; j < 4; ++j) acc[i][j] = (f32x4){0.f, 0.f, 0.f, 0.f};

  int nk = K >> 5;

#define STG5(slot, kt)                                                              \
  do {                                                                              \
    gload16(A + (size_t)(m0 + r0) * K + (kt) * 32 + sc, &SA[slot][tid * 8]);        \
    gload16(A + (size_t)(m0 + 64 + r0) * K + (kt) * 32 + sc, &SA[slot][2048 + tid * 8]); \
    gload16(Bt + (size_t)(n0 + r0) * K + (kt) * 32 + sc, &SB[slot][tid * 8]);       \
    gload16(Bt + (size_t)(n0 + 64 + r0) * K + (kt) * 32 + sc, &SB[slot][2048 + tid * 8]); \
  } while (0)

  STG5(0, 0);
  STG5(1, 1);
  asm volatile("s_waitcnt vmcnt(4)" ::: "memory");
  __builtin_amdgcn_s_barrier();
  asm volatile("" ::: "memory");

  int cur = 0;
  for (int t = 0; t < nk; ++t) {
    if (t + 2 < nk) {
      int stg = cur + 2; if (stg >= 3) stg -= 3;
      STG5(stg, t + 2);
    }
    short8 af[4], bfr[4];
#pragma unroll
    for (int mi = 0; mi < 4; ++mi)
      af[mi] = *(const short8*)&SA[cur][AIDX(wr + mi * 16 + lr, lg)];
#pragma unroll
    for (int ni = 0; ni < 4; ++ni)
      bfr[ni] = *(const short8*)&SB[cur][AIDX(wc + ni * 16 + lr, lg)];
    __builtin_amdgcn_s_setprio(1);
#pragma unroll
    for (int mi = 0; mi < 4; ++mi)
#pragma unroll
      for (int ni = 0; ni < 4; ++ni)
        acc[mi][ni] = __builtin_amdgcn_mfma_f32_16x16x32_bf16(af[mi], bfr[ni], acc[mi][ni], 0, 0, 0);
    __builtin_amdgcn_s_setprio(0);
    if (t + 2 < nk)
      asm volatile("s_waitcnt vmcnt(4)" ::: "memory");
    else if (t + 1 < nk)
      asm volatile("s_waitcnt vmcnt(0)" ::: "memory");
    __builtin_amdgcn_s_barrier();
    asm volatile("" ::: "memory");
    ++cur; if (cur == 3) cur = 0;
  }
#undef STG5

  int rg = lg * 4;
#pragma unroll
  for (int mi = 0; mi < 4; ++mi) {
#pragma unroll
    for (int ni = 0; ni < 4; ++ni) {
      int col = n0 + wc + ni * 16 + lr;
      float bv = bias[col];
#pragma unroll
      for (int j = 0; j < 4; ++j) {
        int row = m0 + wr + mi * 16 + rg + j;
        float o = acc[mi][ni][j] + bv;
        if (OUT_BF16) ((u16*)Cout)[(size_t)row * N + col] = f2bf(o);
        else ((float*)Cout)[(size_t)row * N + col] = o;
      }
    }
  }
}

// ----------------- sliding-window flash attention (v7) -----------------
__global__ __launch_bounds__(256) void k_attn7(
    const u16* __restrict__ Qn, const u16* __restrict__ Kn,
    const u16* __restrict__ Vt, u16* __restrict__ attb) {
  __shared__ __attribute__((aligned(16))) u16 KL[2][4096];  // [key][d] swz
  __shared__ __attribute__((aligned(16))) u16 VL[2][4096];  // [d][key] swz
  __shared__ __attribute__((aligned(16))) u16 Pl[4][2304];  // per-wave 32x72
  int bid = blockIdx.x;
  int xcd = bid & 7, idx = bid >> 3;     // idx in [0,64)
  int bh = xcd * 4 + (idx & 3);
  int qb = 15 - (idx >> 2);              // 128-row tile, big-first
  int q0 = qb * 128;
  int tid = threadIdx.x, lane = tid & 63, w = tid >> 6;
  int ln15 = lane & 15, lg = lane >> 4;
  int qlo = q0 + w * 32;                 // wave's 32 q rows
  const u16* Qh = Qn + (size_t)bh * (2048 * 64);
  const u16* Kh = Kn + (size_t)bh * (2048 * 64);
  const u16* Vh = Vt + (size_t)bh * (64 * 2048);
  int rsw = (ln15 & 7) << 3;
  int srow = tid >> 3;
  int scb = ((tid & 7) ^ ((tid >> 3) & 7)) * 8;

  short8 qf[2][2];
#pragma unroll
  for (int qs = 0; qs < 2; ++qs)
#pragma unroll
    for (int h2 = 0; h2 < 2; ++h2)
      qf[qs][h2] = *(const short8*)(Qh + (size_t)(qlo + qs * 16 + ln15) * 64 + h2 * 32 + lg * 8);

  f32x4 oacc[2][4];
#pragma unroll
  for (int qs = 0; qs < 2; ++qs)
#pragma unroll
    for (int dt = 0; dt < 4; ++dt) oacc[qs][dt] = (f32x4){0.f, 0.f, 0.f, 0.f};
  float lwp[2][4];
#pragma unroll
  for (int qs = 0; qs < 2; ++qs)
#pragma unroll
    for (int j = 0; j < 4; ++j) lwp[qs][j] = 0.f;

  int t0 = q0 >= 512 ? (q0 - 511) >> 6 : 0;
  int t1 = (q0 + 127) >> 6;

#define STAGE_A7(buf, kt)                                                              \
  do {                                                                                 \
    const u16* Kt_ = Kh + (size_t)(kt) * 4096;                                         \
    gload16(Kt_ + (size_t)srow * 64 + scb, &KL[buf][tid * 8]);                         \
    gload16(Kt_ + (size_t)(srow + 32) * 64 + scb, &KL[buf][2048 + tid * 8]);           \
    const u16* Vt_ = Vh + (size_t)(kt) * 64;                                           \
    gload16(Vt_ + (size_t)srow * 2048 + scb, &VL[buf][tid * 8]);                       \
    gload16(Vt_ + (size_t)(srow + 32) * 2048 + scb, &VL[buf][2048 + tid * 8]);         \
  } while (0)

  STAGE_A7(0, t0);
  asm volatile("s_waitcnt vmcnt(0)" ::: "memory");
  __syncthreads();

  for (int t = t0; t <= t1; ++t) {
    int cur = (t - t0) & 1;
    if (t + 1 <= t1) STAGE_A7(cur ^ 1, t + 1);
    int kt6 = t * 64;
    // wave-uniform: tile intersects this wave's 32-row window?
    if (kt6 <= qlo + 31 && kt6 + 63 >= qlo - 511) {
      short8 kf[4][2];
#pragma unroll
      for (int c = 0; c < 4; ++c)
#pragma unroll
        for (int h2 = 0; h2 < 2; ++h2)
          kf[c][h2] = *(const short8*)&KL[cur][((c * 16 + ln15) * 64 + h2 * 32 + lg * 8) ^ rsw];
      f32x4 sf[2][4];
      __builtin_amdgcn_s_setprio(1);
#pragma unroll
      for (int qs = 0; qs < 2; ++qs)
#pragma unroll
        for (int c = 0; c < 4; ++c) {
          f32x4 z = (f32x4){0.f, 0.f, 0.f, 0.f};
          z = __builtin_amdgcn_mfma_f32_16x16x32_bf16(qf[qs][0], kf[c][0], z, 0, 0, 0);
          sf[qs][c] = __builtin_amdgcn_mfma_f32_16x16x32_bf16(qf[qs][1], kf[c][1], z, 0, 0, 0);
        }
      __builtin_amdgcn_s_setprio(0);
      bool interior = (kt6 + 63 <= qlo) && (kt6 >= qlo - 480);
      if (interior) {
#pragma unroll
        for (int qs = 0; qs < 2; ++qs)
#pragma unroll
          for (int c = 0; c < 4; ++c)
#pragma unroll
            for (int j = 0; j < 4; ++j) {
              float p = __builtin_amdgcn_exp2f(sf[qs][c][j]);
              sf[qs][c][j] = p;
              lwp[qs][j] += p;
            }
      } else {
#pragma unroll
        for (int qs = 0; qs < 2; ++qs)
#pragma unroll
          for (int c = 0; c < 4; ++c) {
            int kk = kt6 + c * 16 + ln15;
#pragma unroll
            for (int j = 0; j < 4; ++j) {
              int q = qlo + qs * 16 + lg * 4 + j;
              bool msk = (kk > q) || ((q - kk) >= 512);
              float p = __builtin_amdgcn_exp2f(msk ? -1e30f : sf[qs][c][j]);
              sf[qs][c][j] = p;
              lwp[qs][j] += p;
            }
          }
      }
#pragma unroll
      for (int qs = 0; qs < 2; ++qs)
#pragma unroll
        for (int c = 0; c < 4; ++c)
#pragma unroll
          for (int j = 0; j < 4; ++j) {
            uint32_t u = __float_as_uint(sf[qs][c][j]);
            Pl[w][(qs * 16 + lg * 4 + j) * 72 + c * 16 + ln15] = (u16)((u + 0x8000u) >> 16);
          }
      short8 vf[4][2];
#pragma unroll
      for (int dt = 0; dt < 4; ++dt)
#pragma unroll
        for (int h2 = 0; h2 < 2; ++h2)
          vf[dt][h2] = *(const short8*)&VL[cur][((dt * 16 + ln15) * 64 + h2 * 32 + lg * 8) ^ rsw];
      __builtin_amdgcn_s_setprio(1);
#pragma unroll
      for (int qs = 0; qs < 2; ++qs)
#pragma unroll
        for (int h2 = 0; h2 < 2; ++h2) {
          short8 pf = *(const short8*)&Pl[w][(qs * 16 + ln15) * 72 + h2 * 32 + lg * 8];
#pragma unroll
          for (int dt = 0; dt < 4; ++dt)
            oacc[qs][dt] = __builtin_amdgcn_mfma_f32_16x16x32_bf16(pf, vf[dt][h2], oacc[qs][dt], 0, 0, 0);
        }
      __builtin_amdgcn_s_setprio(0);
    }
    asm volatile("s_waitcnt vmcnt(0)" ::: "memory");
    __syncthreads();
  }
#undef STAGE_A7

  int b = bh >> 4, hh = bh & 15;
#pragma unroll
  for (int qs = 0; qs < 2; ++qs)
#pragma unroll
    for (int j = 0; j < 4; ++j) {
      float rs = lwp[qs][j];
#pragma unroll
      for (int m = 8; m > 0; m >>= 1) rs += __shfl_xor(rs, m, 64);
      float inv = rs > 0.f ? 1.f / rs : 0.f;
      int row = b * 2048 + qlo + qs * 16 + lg * 4 + j;
#pragma unroll
      for (int dt = 0; dt < 4; ++dt)
        attb[(size_t)row * 1024 + hh * 64 + dt * 16 + ln15] = f2bf(oacc[qs][dt][j] * inv);
    }
}

extern "C" void kernel_launch(void* const* d_in, const int* in_sizes, int n_in,
                              void* d_out, int out_size, void* d_ws, size_t ws_size,
                              hipStream_t stream) {
  const float* x = (const float*)d_in[0];
  const float* Wqkv = (const float*)d_in[1];
  const float* bqkv = (const float*)d_in[2];
  const float* qg = (const float*)d_in[3];
  const float* qb = (const float*)d_in[4];
  const float* kg = (const float*)d_in[5];
  const float* kb = (const float*)d_in[6];
  const float* Wout = (const float*)d_in[7];
  const float* bout = (const float*)d_in[8];
  float* out = (float*)d_out;

  char* ws = (char*)d_ws;
  u16* attb = (u16*)(ws);                    // 8,388,608
  u16* Vt = (u16*)(ws + 8388608);            // 8,388,608
  u16* Qn = (u16*)(ws + 16777216);           // 8,388,608
  u16* Kn = (u16*)(ws + 25165824);           // 8,388,608
  u16* xb = (u16*)(ws + 33554432);           // 8,388,608
  u16* wqkvT = (u16*)(ws + 41943040);        // 6,291,456
  u16* woutT = (u16*)(ws + 48234496);        // 2,097,152  (total 50,331,648)

  // 1. fused prep: x cast + both weight transposes (one launch)
  k_prep<<<5120, 256, 0, stream>>>(x, xb, Wqkv, wqkvT, Wout, woutT);
  // 2. fused QKV GEMM + bias + qk-LN + head-split + V-transpose (ring-3)
  k_gemmqkv<<<768, 256, 0, stream>>>(xb, wqkvT, bqkv, qg, qb, kg, kb, Qn, Kn, Vt);
  // 3. sliding-window attention -> (B,S,E) bf16  (128-row blocks)
  k_attn7<<<512, 256, 0, stream>>>(Qn, Kn, Vt, attb);
  // 4. output GEMM (+bias) -> fp32 (ring-3)
  k_gemm5<0><<<256, 256, 0, stream>>>(attb, woutT, bout, out, 4096, 1024, 1024);
}

// Round 17
// 96.235 us; speedup vs baseline: 1.1922x; 1.1922x over previous
//
#include <hip/hip_runtime.h>
#include <stdint.h>

typedef uint16_t u16;
typedef __attribute__((ext_vector_type(8))) short short8;
typedef __attribute__((ext_vector_type(4))) float f32x4;

#define DEV static __device__ __forceinline__

DEV u16 f2bf(float f) {
  uint32_t u = __float_as_uint(f);
  return (u16)((u + 0x7fffu + ((u >> 16) & 1u)) >> 16);
}
DEV float bf2f(u16 h) { return __uint_as_float(((uint32_t)h) << 16); }

DEV void gload16(const void* g, void* l) {
  __builtin_amdgcn_global_load_lds(
      (const __attribute__((address_space(1))) void*)g,
      (__attribute__((address_space(3))) void*)l, 16, 0, 0);
}

// ---- fused prep: x cast 32B/thread (blocks 0..2047), Wqkv^T (2048..2815),
// ---- Wout^T (2816..3071). One launch.
__global__ void k_prep(const float* __restrict__ x, u16* __restrict__ xb,
                       const float* __restrict__ Wqkv, u16* __restrict__ wqkvT,
                       const float* __restrict__ Wout, u16* __restrict__ woutT) {
  __shared__ u16 t[64][65];
  int b = blockIdx.x, tid = threadIdx.x;
  if (b < 2048) {
    int i = (b * 256 + tid) * 2;
#pragma unroll
    for (int k = 0; k < 2; ++k) {
      float4 v = ((const float4*)x)[i + k];
      uint2 p;
      p.x = (uint32_t)f2bf(v.x) | ((uint32_t)f2bf(v.y) << 16);
      p.y = (uint32_t)f2bf(v.z) | ((uint32_t)f2bf(v.w) << 16);
      ((uint2*)xb)[i + k] = p;
    }
    return;
  }
  const float* Wm;
  u16* Wt;
  int id, NX;
  if (b < 2816) { Wm = Wqkv; Wt = wqkvT; id = b - 2048; NX = 48; }
  else          { Wm = Wout; Wt = woutT; id = b - 2816; NX = 16; }
  int n0 = (id % NX) * 64, k0 = (id / NX) * 64;
  int K = 1024, N = NX * 64;
#pragma unroll
  for (int i = 0; i < 16; ++i) {
    int idx = tid + i * 256, r = idx >> 6, c = idx & 63;
    t[r][c] = f2bf(Wm[(size_t)(k0 + r) * N + n0 + c]);
  }
  __syncthreads();
#pragma unroll
  for (int i = 0; i < 16; ++i) {
    int idx = tid + i * 256, r = idx >> 6, c = idx & 63;
    Wt[(size_t)(n0 + r) * K + k0 + c] = t[c][r];
  }
}

// ---- fused QKV GEMM (r11/r15-verified): 128x128, BK=64, dbuf, 4 waves,
// ---- 2D XCD chunking (3 B-panels per XCD, L2-resident). 42us / ~620TF:
// ---- measured local optimum for this K=1024 + fused-LN-epilogue shape.
__global__ __launch_bounds__(256) void k_gemmqkv(
    const u16* __restrict__ A, const u16* __restrict__ Bt,
    const float* __restrict__ bias,
    const float* __restrict__ qg, const float* __restrict__ qb,
    const float* __restrict__ kg, const float* __restrict__ kb,
    u16* __restrict__ Qn, u16* __restrict__ Kn, u16* __restrict__ Vt) {
  const int K = 1024, N = 3072;
  __shared__ __attribute__((aligned(16))) u16 S[2][2][128 * 64];  // 64 KiB
  int bid = blockIdx.x;
  int xcd = bid & 7, i = bid >> 3;        // i in [0,96)
  int my = i / 3, nx = xcd * 3 + i % 3;   // 2D chunk: 3 B-panels per XCD
  int m0 = my * 128, n0 = nx * 128;
  int tid = threadIdx.x, lane = tid & 63, w = tid >> 6;
  int wr = (w >> 1) * 64, wc = (w & 1) * 64;
  int lr = lane & 15, lg = lane >> 4;
  int rsw = (lr & 7) << 3;
  int srow = tid >> 3;
  int scb = ((tid & 7) ^ ((tid >> 3) & 7)) * 8;
  f32x4 acc[4][4];
#pragma unroll
  for (int ii = 0; ii < 4; ++ii)
#pragma unroll
    for (int j = 0; j < 4; ++j) acc[ii][j] = (f32x4){0.f, 0.f, 0.f, 0.f};

  int nk = K >> 6;

#define STGQ(buf, kt)                                                                   \
  do {                                                                                  \
    gload16(A + (size_t)(m0 + srow) * K + (kt) * 64 + scb, &S[buf][0][tid * 8]);        \
    gload16(A + (size_t)(m0 + 32 + srow) * K + (kt) * 64 + scb, &S[buf][0][2048 + tid * 8]);  \
    gload16(A + (size_t)(m0 + 64 + srow) * K + (kt) * 64 + scb, &S[buf][0][4096 + tid * 8]);  \
    gload16(A + (size_t)(m0 + 96 + srow) * K + (kt) * 64 + scb, &S[buf][0][6144 + tid * 8]);  \
    gload16(Bt + (size_t)(n0 + srow) * K + (kt) * 64 + scb, &S[buf][1][tid * 8]);       \
    gload16(Bt + (size_t)(n0 + 32 + srow) * K + (kt) * 64 + scb, &S[buf][1][2048 + tid * 8]); \
    gload16(Bt + (size_t)(n0 + 64 + srow) * K + (kt) * 64 + scb, &S[buf][1][4096 + tid * 8]); \
    gload16(Bt + (size_t)(n0 + 96 + srow) * K + (kt) * 64 + scb, &S[buf][1][6144 + tid * 8]); \
  } while (0)

  STGQ(0, 0);
  asm volatile("s_waitcnt vmcnt(0)" ::: "memory");
  __syncthreads();

  for (int t = 0; t < nk; ++t) {
    int cur = t & 1;
    if (t + 1 < nk) STGQ(cur ^ 1, t + 1);
#pragma unroll
    for (int ks = 0; ks < 2; ++ks) {
      short8 af[4], bf[4];
#pragma unroll
      for (int mi = 0; mi < 4; ++mi)
        af[mi] = *(const short8*)&S[cur][0][((wr + mi * 16 + lr) * 64 + ks * 32 + lg * 8) ^ rsw];
#pragma unroll
      for (int ni = 0; ni < 4; ++ni)
        bf[ni] = *(const short8*)&S[cur][1][((wc + ni * 16 + lr) * 64 + ks * 32 + lg * 8) ^ rsw];
      __builtin_amdgcn_s_setprio(1);
#pragma unroll
      for (int mi = 0; mi < 4; ++mi)
#pragma unroll
        for (int ni = 0; ni < 4; ++ni)
          acc[mi][ni] = __builtin_amdgcn_mfma_f32_16x16x32_bf16(af[mi], bf[ni], acc[mi][ni], 0, 0, 0);
      __builtin_amdgcn_s_setprio(0);
    }
    asm volatile("s_waitcnt vmcnt(0)" ::: "memory");
    __syncthreads();
  }
#undef STGQ

  int rg = lg * 4;
  int sec = n0 >> 10;                       // 0=Q, 1=K, 2=V
  int hh = ((n0 + wc) >> 6) & 15;           // head for this wave
  int b = m0 >> 11;
  int s0 = m0 & 2047;

  if (sec < 2) {
    const float* gp = sec ? kg : qg;
    const float* bp = sec ? kb : qb;
    float scl = sec ? 1.f : (0.125f * 1.44269504f);  // Q: fold 1/sqrt(D)*log2e
    u16* op = sec ? Kn : Qn;
    float gv[4], bev[4], bb[4];
#pragma unroll
    for (int ni = 0; ni < 4; ++ni) {
      int d = ni * 16 + lr;
      gv[ni] = gp[d];
      bev[ni] = bp[d];
      bb[ni] = bias[n0 + wc + d];
    }
    size_t hb = (size_t)(b * 16 + hh) * 2048 * 64;
#pragma unroll
    for (int mi = 0; mi < 4; ++mi) {
      float a[4][4], ps[4], ps2[4];
#pragma unroll
      for (int ni = 0; ni < 4; ++ni)
#pragma unroll
        for (int j = 0; j < 4; ++j) a[ni][j] = acc[mi][ni][j] + bb[ni];
#pragma unroll
      for (int j = 0; j < 4; ++j) {
        ps[j] = a[0][j] + a[1][j] + a[2][j] + a[3][j];
        ps2[j] = a[0][j] * a[0][j] + a[1][j] * a[1][j] + a[2][j] * a[2][j] + a[3][j] * a[3][j];
      }
#pragma unroll
      for (int m = 1; m < 16; m <<= 1)
#pragma unroll
        for (int j = 0; j < 4; ++j) {
          ps[j] += __shfl_xor(ps[j], m, 64);
          ps2[j] += __shfl_xor(ps2[j], m, 64);
        }
#pragma unroll
      for (int j = 0; j < 4; ++j) {
        float mean = ps[j] * (1.f / 64);
        float var = ps2[j] * (1.f / 64) - mean * mean;
        float r = rsqrtf(var + 1e-5f);
        int row = s0 + wr + mi * 16 + rg + j;
        size_t base = hb + (size_t)row * 64;
#pragma unroll
        for (int ni = 0; ni < 4; ++ni) {
          float v = ((a[ni][j] - mean) * r * gv[ni] + bev[ni]) * scl;
          op[base + ni * 16 + lr] = f2bf(v);
        }
      }
    }
  } else {
    // V: direct transposed store Vt[bh][d][s], 8B packed (4 consecutive s)
    u16* vbase = Vt + (size_t)(b * 16 + hh) * 64 * 2048;
#pragma unroll
    for (int ni = 0; ni < 4; ++ni) {
      int d = ni * 16 + lr;
      float bb = bias[n0 + wc + d];
#pragma unroll
      for (int mi = 0; mi < 4; ++mi) {
        int row0 = s0 + wr + mi * 16 + rg;
        uint2 pk;
        pk.x = (uint32_t)f2bf(acc[mi][ni][0] + bb) | ((uint32_t)f2bf(acc[mi][ni][1] + bb) << 16);
        pk.y = (uint32_t)f2bf(acc[mi][ni][2] + bb) | ((uint32_t)f2bf(acc[mi][ni][3] + bb) << 16);
        *(uint2*)(vbase + (size_t)d * 2048 + row0) = pk;
      }
    }
  }
}

// ---- GEMM v4: 128x128 tile, BK=64, double-buffer, 4 waves (GEMM2) -----
template <int OUT_BF16>
__global__ __launch_bounds__(256) void k_gemm4(
    const u16* __restrict__ A, const u16* __restrict__ Bt,
    const float* __restrict__ bias, void* __restrict__ Cout,
    int M, int N, int K) {
  __shared__ __attribute__((aligned(16))) u16 S[2][2][128 * 64];  // 64 KiB
  int bid = blockIdx.x;
  int ntn = N >> 7;
  int cpx = gridDim.x >> 3;
  int wg = (bid & 7) * cpx + (bid >> 3);
  int my = wg / ntn, nx = wg - my * ntn;
  int m0 = my * 128, n0 = nx * 128;
  int tid = threadIdx.x, lane = tid & 63, w = tid >> 6;
  int wr = (w >> 1) * 64, wc = (w & 1) * 64;
  int lr = lane & 15, lg = lane >> 4;
  int rsw = (lr & 7) << 3;
  int srow = tid >> 3;
  int scb = ((tid & 7) ^ ((tid >> 3) & 7)) * 8;
  f32x4 acc[4][4];
#pragma unroll
  for (int i = 0; i < 4; ++i)
#pragma unroll
    for (int j = 0; j < 4; ++j) acc[i][j] = (f32x4){0.f, 0.f, 0.f, 0.f};

  int nk = K >> 6;

#define STG4(buf, kt)                                                                   \
  do {                                                                                  \
    gload16(A + (size_t)(m0 + srow) * K + (kt) * 64 + scb, &S[buf][0][tid * 8]);        \
    gload16(A + (size_t)(m0 + 32 + srow) * K + (kt) * 64 + scb, &S[buf][0][2048 + tid * 8]);  \
    gload16(A + (size_t)(m0 + 64 + srow) * K + (kt) * 64 + scb, &S[buf][0][4096 + tid * 8]);  \
    gload16(A + (size_t)(m0 + 96 + srow) * K + (kt) * 64 + scb, &S[buf][0][6144 + tid * 8]);  \
    gload16(Bt + (size_t)(n0 + srow) * K + (kt) * 64 + scb, &S[buf][1][tid * 8]);       \
    gload16(Bt + (size_t)(n0 + 32 + srow) * K + (kt) * 64 + scb, &S[buf][1][2048 + tid * 8]); \
    gload16(Bt + (size_t)(n0 + 64 + srow) * K + (kt) * 64 + scb, &S[buf][1][4096 + tid * 8]); \
    gload16(Bt + (size_t)(n0 + 96 + srow) * K + (kt) * 64 + scb, &S[buf][1][6144 + tid * 8]); \
  } while (0)

  STG4(0, 0);
  asm volatile("s_waitcnt vmcnt(0)" ::: "memory");
  __syncthreads();

  for (int t = 0; t < nk; ++t) {
    int cur = t & 1;
    if (t + 1 < nk) STG4(cur ^ 1, t + 1);
#pragma unroll
    for (int ks = 0; ks < 2; ++ks) {
      short8 af[4], bf[4];
#pragma unroll
      for (int mi = 0; mi < 4; ++mi)
        af[mi] = *(const short8*)&S[cur][0][((wr + mi * 16 + lr) * 64 + ks * 32 + lg * 8) ^ rsw];
#pragma unroll
      for (int ni = 0; ni < 4; ++ni)
        bf[ni] = *(const short8*)&S[cur][1][((wc + ni * 16 + lr) * 64 + ks * 32 + lg * 8) ^ rsw];
      __builtin_amdgcn_s_setprio(1);
#pragma unroll
      for (int mi = 0; mi < 4; ++mi)
#pragma unroll
        for (int ni = 0; ni < 4; ++ni)
          acc[mi][ni] = __builtin_amdgcn_mfma_f32_16x16x32_bf16(af[mi], bf[ni], acc[mi][ni], 0, 0, 0);
      __builtin_amdgcn_s_setprio(0);
    }
    asm volatile("s_waitcnt vmcnt(0)" ::: "memory");
    __syncthreads();
  }
#undef STG4

  int rg = lg * 4;
#pragma unroll
  for (int mi = 0; mi < 4; ++mi) {
#pragma unroll
    for (int ni = 0; ni < 4; ++ni) {
      int col = n0 + wc + ni * 16 + lr;
      float bv = bias[col];
#pragma unroll
      for (int j = 0; j < 4; ++j) {
        int row = m0 + wr + mi * 16 + rg + j;
        float o = acc[mi][ni][j] + bv;
        if (OUT_BF16) ((u16*)Cout)[(size_t)row * N + col] = f2bf(o);
        else ((float*)Cout)[(size_t)row * N + col] = o;
      }
    }
  }
}

// ----------------- sliding-window flash attention (v7) -----------------
__global__ __launch_bounds__(256) void k_attn7(
    const u16* __restrict__ Qn, const u16* __restrict__ Kn,
    const u16* __restrict__ Vt, u16* __restrict__ attb) {
  __shared__ __attribute__((aligned(16))) u16 KL[2][4096];  // [key][d] swz
  __shared__ __attribute__((aligned(16))) u16 VL[2][4096];  // [d][key] swz
  __shared__ __attribute__((aligned(16))) u16 Pl[4][2304];  // per-wave 32x72
  int bid = blockIdx.x;
  int xcd = bid & 7, idx = bid >> 3;     // idx in [0,64)
  int bh = xcd * 4 + (idx & 3);
  int qb = 15 - (idx >> 2);              // 128-row tile, big-first
  int q0 = qb * 128;
  int tid = threadIdx.x, lane = tid & 63, w = tid >> 6;
  int ln15 = lane & 15, lg = lane >> 4;
  int qlo = q0 + w * 32;                 // wave's 32 q rows
  const u16* Qh = Qn + (size_t)bh * (2048 * 64);
  const u16* Kh = Kn + (size_t)bh * (2048 * 64);
  const u16* Vh = Vt + (size_t)bh * (64 * 2048);
  int rsw = (ln15 & 7) << 3;
  int srow = tid >> 3;
  int scb = ((tid & 7) ^ ((tid >> 3) & 7)) * 8;

  short8 qf[2][2];
#pragma unroll
  for (int qs = 0; qs < 2; ++qs)
#pragma unroll
    for (int h2 = 0; h2 < 2; ++h2)
      qf[qs][h2] = *(const short8*)(Qh + (size_t)(qlo + qs * 16 + ln15) * 64 + h2 * 32 + lg * 8);

  f32x4 oacc[2][4];
#pragma unroll
  for (int qs = 0; qs < 2; ++qs)
#pragma unroll
    for (int dt = 0; dt < 4; ++dt) oacc[qs][dt] = (f32x4){0.f, 0.f, 0.f, 0.f};
  float lwp[2][4];
#pragma unroll
  for (int qs = 0; qs < 2; ++qs)
#pragma unroll
    for (int j = 0; j < 4; ++j) lwp[qs][j] = 0.f;

  int t0 = q0 >= 512 ? (q0 - 511) >> 6 : 0;
  int t1 = (q0 + 127) >> 6;

#define STAGE_A7(buf, kt)                                                              \
  do {                                                                                 \
    const u16* Kt_ = Kh + (size_t)(kt) * 4096;                                         \
    gload16(Kt_ + (size_t)srow * 64 + scb, &KL[buf][tid * 8]);                         \
    gload16(Kt_ + (size_t)(srow + 32) * 64 + scb, &KL[buf][2048 + tid * 8]);           \
    const u16* Vt_ = Vh + (size_t)(kt) * 64;                                           \
    gload16(Vt_ + (size_t)srow * 2048 + scb, &VL[buf][tid * 8]);                       \
    gload16(Vt_ + (size_t)(srow + 32) * 2048 + scb, &VL[buf][2048 + tid * 8]);         \
  } while (0)

  STAGE_A7(0, t0);
  asm volatile("s_waitcnt vmcnt(0)" ::: "memory");
  __syncthreads();

  for (int t = t0; t <= t1; ++t) {
    int cur = (t - t0) & 1;
    if (t + 1 <= t1) STAGE_A7(cur ^ 1, t + 1);
    int kt6 = t * 64;
    // wave-uniform: tile intersects this wave's 32-row window?
    if (kt6 <= qlo + 31 && kt6 + 63 >= qlo - 511) {
      short8 kf[4][2];
#pragma unroll
      for (int c = 0; c < 4; ++c)
#pragma unroll
        for (int h2 = 0; h2 < 2; ++h2)
          kf[c][h2] = *(const short8*)&KL[cur][((c * 16 + ln15) * 64 + h2 * 32 + lg * 8) ^ rsw];
      f32x4 sf[2][4];
      __builtin_amdgcn_s_setprio(1);
#pragma unroll
      for (int qs = 0; qs < 2; ++qs)
#pragma unroll
        for (int c = 0; c < 4; ++c) {
          f32x4 z = (f32x4){0.f, 0.f, 0.f, 0.f};
          z = __builtin_amdgcn_mfma_f32_16x16x32_bf16(qf[qs][0], kf[c][0], z, 0, 0, 0);
          sf[qs][c] = __builtin_amdgcn_mfma_f32_16x16x32_bf16(qf[qs][1], kf[c][1], z, 0, 0, 0);
        }
      __builtin_amdgcn_s_setprio(0);
      bool interior = (kt6 + 63 <= qlo) && (kt6 >= qlo - 480);
      if (interior) {
#pragma unroll
        for (int qs = 0; qs < 2; ++qs)
#pragma unroll
          for (int c = 0; c < 4; ++c)
#pragma unroll
            for (int j = 0; j < 4; ++j) {
              float p = __builtin_amdgcn_exp2f(sf[qs][c][j]);
              sf[qs][c][j] = p;
              lwp[qs][j] += p;
            }
      } else {
#pragma unroll
        for (int qs = 0; qs < 2; ++qs)
#pragma unroll
          for (int c = 0; c < 4; ++c) {
            int kk = kt6 + c * 16 + ln15;
#pragma unroll
            for (int j = 0; j < 4; ++j) {
              int q = qlo + qs * 16 + lg * 4 + j;
              bool msk = (kk > q) || ((q - kk) >= 512);
              float p = __builtin_amdgcn_exp2f(msk ? -1e30f : sf[qs][c][j]);
              sf[qs][c][j] = p;
              lwp[qs][j] += p;
            }
          }
      }
#pragma unroll
      for (int qs = 0; qs < 2; ++qs)
#pragma unroll
        for (int c = 0; c < 4; ++c)
#pragma unroll
          for (int j = 0; j < 4; ++j) {
            uint32_t u = __float_as_uint(sf[qs][c][j]);
            Pl[w][(qs * 16 + lg * 4 + j) * 72 + c * 16 + ln15] = (u16)((u + 0x8000u) >> 16);
          }
      short8 vf[4][2];
#pragma unroll
      for (int dt = 0; dt < 4; ++dt)
#pragma unroll
        for (int h2 = 0; h2 < 2; ++h2)
          vf[dt][h2] = *(const short8*)&VL[cur][((dt * 16 + ln15) * 64 + h2 * 32 + lg * 8) ^ rsw];
      __builtin_amdgcn_s_setprio(1);
#pragma unroll
      for (int qs = 0; qs < 2; ++qs)
#pragma unroll
        for (int h2 = 0; h2 < 2; ++h2) {
          short8 pf = *(const short8*)&Pl[w][(qs * 16 + ln15) * 72 + h2 * 32 + lg * 8];
#pragma unroll
          for (int dt = 0; dt < 4; ++dt)
            oacc[qs][dt] = __builtin_amdgcn_mfma_f32_16x16x32_bf16(pf, vf[dt][h2], oacc[qs][dt], 0, 0, 0);
        }
      __builtin_amdgcn_s_setprio(0);
    }
    asm volatile("s_waitcnt vmcnt(0)" ::: "memory");
    __syncthreads();
  }
#undef STAGE_A7

  int b = bh >> 4, hh = bh & 15;
#pragma unroll
  for (int qs = 0; qs < 2; ++qs)
#pragma unroll
    for (int j = 0; j < 4; ++j) {
      float rs = lwp[qs][j];
#pragma unroll
      for (int m = 8; m > 0; m >>= 1) rs += __shfl_xor(rs, m, 64);
      float inv = rs > 0.f ? 1.f / rs : 0.f;
      int row = b * 2048 + qlo + qs * 16 + lg * 4 + j;
#pragma unroll
      for (int dt = 0; dt < 4; ++dt)
        attb[(size_t)row * 1024 + hh * 64 + dt * 16 + ln15] = f2bf(oacc[qs][dt][j] * inv);
    }
}

extern "C" void kernel_launch(void* const* d_in, const int* in_sizes, int n_in,
                              void* d_out, int out_size, void* d_ws, size_t ws_size,
                              hipStream_t stream) {
  const float* x = (const float*)d_in[0];
  const float* Wqkv = (const float*)d_in[1];
  const float* bqkv = (const float*)d_in[2];
  const float* qg = (const float*)d_in[3];
  const float* qb = (const float*)d_in[4];
  const float* kg = (const float*)d_in[5];
  const float* kb = (const float*)d_in[6];
  const float* Wout = (const float*)d_in[7];
  const float* bout = (const float*)d_in[8];
  float* out = (float*)d_out;

  char* ws = (char*)d_ws;
  u16* attb = (u16*)(ws);                    // 8,388,608
  u16* Vt = (u16*)(ws + 8388608);            // 8,388,608
  u16* Qn = (u16*)(ws + 16777216);           // 8,388,608
  u16* Kn = (u16*)(ws + 25165824);           // 8,388,608
  u16* xb = (u16*)(ws + 33554432);           // 8,388,608
  u16* wqkvT = (u16*)(ws + 41943040);        // 6,291,456
  u16* woutT = (u16*)(ws + 48234496);        // 2,097,152  (total 50,331,648)

  // 1. fused prep: x cast + both weight transposes (one launch)
  k_prep<<<3072, 256, 0, stream>>>(x, xb, Wqkv, wqkvT, Wout, woutT);
  // 2. fused QKV GEMM + bias + qk-LN + head-split + V-transpose
  k_gemmqkv<<<768, 256, 0, stream>>>(xb, wqkvT, bqkv, qg, qb, kg, kb, Qn, Kn, Vt);
  // 3. sliding-window attention -> (B,S,E) bf16  (128-row blocks)
  k_attn7<<<512, 256, 0, stream>>>(Qn, Kn, Vt, attb);
  // 4. output GEMM (+bias) -> fp32
  k_gemm4<0><<<256, 256, 0, stream>>>(attb, woutT, bout, out, 4096, 1024, 1024);
}